// Round 1
// baseline (1539.667 us; speedup 1.0000x reference)
//
#include <hip/hip_runtime.h>

#define T_SEQ 25
#define NBATCH 4096
#define D_IN 500
#define HID 64
#define NG 256
#define NLAYERS 25
#define NOUT 10

typedef __attribute__((ext_vector_type(8))) short bf16x8;
typedef __attribute__((ext_vector_type(4))) short bf16x4;
typedef __attribute__((ext_vector_type(4))) float f32x4;

#define LOG2E 1.4426950408889634f

// LDS geometry for lstm_persist: slot = 16 rows x 72 shorts (64 h + 8 pad)
#define SLOT 1152
#define RING_STRIDE (4*SLOT)      // 3 small rings, 4 slots each
#define WRAP_OFF (3*RING_STRIDE)  // 13824: wrap ring, 26 slots
#define LDS_SHORTS (WRAP_OFF + 26*SLOT)  // 43776 shorts = 87.5 KB

__device__ __forceinline__ short f2bf(float f) {
    union { float f; unsigned u; } v; v.f = f;
    unsigned u = v.u + 0x7FFFu + ((v.u >> 16) & 1u);   // RNE
    return (short)(u >> 16);
}
__device__ __forceinline__ float bf2f(short s) {
    union { unsigned u; float f; } v;
    v.u = ((unsigned)(unsigned short)s) << 16;
    return v.f;
}
__device__ __forceinline__ bf16x8 cvt8(f32x4 a, f32x4 b) {
    bf16x8 r;
    r[0]=f2bf(a[0]); r[1]=f2bf(a[1]); r[2]=f2bf(a[2]); r[3]=f2bf(a[3]);
    r[4]=f2bf(b[0]); r[5]=f2bf(b[1]); r[6]=f2bf(b[2]); r[7]=f2bf(b[3]);
    return r;
}

// ---------------------------------------------------------------------------
// prep: weights -> bf16 images (unchanged).
// ---------------------------------------------------------------------------
__global__ __launch_bounds__(256)
void prep(const float* __restrict__ Wih0, const float* __restrict__ Whh0,
          const float* __restrict__ WihR, const float* __restrict__ WhhR,
          const float* __restrict__ bihR, const float* __restrict__ bhhR,
          short* __restrict__ wbf2, short* __restrict__ whh0b,
          short* __restrict__ wihRb, short* __restrict__ whhRb,
          float* __restrict__ bsum) {
    int idx = blockIdx.x * 256 + threadIdx.x;
    if (idx < 131072) {
        int j = idx & 7, lane = (idx >> 3) & 63, nt = (idx >> 9) & 15, kc = idx >> 13;
        int n = nt*16 + (lane & 15);
        int k = kc*32 + (lane >> 4)*8 + j;
        wbf2[idx] = (k < D_IN) ? f2bf(Wih0[n * D_IN + k]) : (short)0;
    } else if (idx < 147456) {
        int j = idx - 131072; whh0b[j] = f2bf(Whh0[j]);
    } else if (idx < 540672) {
        int j = idx - 147456; wihRb[j] = f2bf(WihR[j]);
    } else if (idx < 933888) {
        int j = idx - 540672; whhRb[j] = f2bf(WhhR[j]);
    } else if (idx < 940032) {
        int j = idx - 933888; bsum[j] = bihR[j] + bhhR[j];
    }
}

// ---------------------------------------------------------------------------
// Kernel A: xp0[t][g][b] (bf16) = x·W_ih0^T + bih0 + bhh0 (unchanged).
// ---------------------------------------------------------------------------
__global__ __launch_bounds__(256, 1)
void xp0_gemm(const float* __restrict__ x, const short* __restrict__ wbf2,
              const float* __restrict__ bih0, const float* __restrict__ bhh0,
              short* __restrict__ xp0b) {
    const int tid = threadIdx.x;
    const int wv = tid >> 6, lane = tid & 63, col = lane & 15, q = lane >> 4;
    const int t  = blockIdx.x >> 5;           // 32 M-tiles per t
    const int b0 = (blockIdx.x & 31) << 7;    // 128-row b tile

    f32x4 acc[2][16];
    #pragma unroll
    for (int nt = 0; nt < 16; nt++) {
        int g = nt*16 + col;
        float bv = bih0[g] + bhh0[g];
        acc[0][nt] = (f32x4){bv,bv,bv,bv};
        acc[1][nt] = acc[0][nt];
    }
    const float* xrow0 = x + ((size_t)t*NBATCH + b0 + wv*32 + col)*D_IN;
    const float* xrow1 = xrow0 + 16*(size_t)D_IN;

    #pragma unroll 3
    for (int kc = 0; kc < 15; kc++) {
        const int ko = kc*32 + q*8;
        const f32x4* p0 = (const f32x4*)(xrow0 + ko);
        const f32x4* p1 = (const f32x4*)(xrow1 + ko);
        bf16x8 a0 = cvt8(p0[0], p0[1]);
        bf16x8 a1 = cvt8(p1[0], p1[1]);
        #pragma unroll
        for (int nt = 0; nt < 16; nt++) {
            bf16x8 bfr = *(const bf16x8*)(wbf2 + ((size_t)(kc*16+nt)*64 + lane)*8);
            acc[0][nt] = __builtin_amdgcn_mfma_f32_16x16x32_bf16(a0, bfr, acc[0][nt], 0,0,0);
            acc[1][nt] = __builtin_amdgcn_mfma_f32_16x16x32_bf16(a1, bfr, acc[1][nt], 0,0,0);
        }
    }
    {   // K tail kc=15: k=480..511, valid < 500
        f32x4 z = (f32x4){0.f,0.f,0.f,0.f};
        f32x4 lo0=z, hi0=z, lo1=z, hi1=z;
        const int ko = 480 + q*8;
        if (q < 2) {
            lo0 = *(const f32x4*)(xrow0 + ko); hi0 = *(const f32x4*)(xrow0 + ko + 4);
            lo1 = *(const f32x4*)(xrow1 + ko); hi1 = *(const f32x4*)(xrow1 + ko + 4);
        } else if (q == 2) {
            lo0 = *(const f32x4*)(xrow0 + 496);
            lo1 = *(const f32x4*)(xrow1 + 496);
        }
        bf16x8 a0 = cvt8(lo0, hi0);
        bf16x8 a1 = cvt8(lo1, hi1);
        #pragma unroll
        for (int nt = 0; nt < 16; nt++) {
            bf16x8 bfr = *(const bf16x8*)(wbf2 + ((size_t)(15*16+nt)*64 + lane)*8);
            acc[0][nt] = __builtin_amdgcn_mfma_f32_16x16x32_bf16(a0, bfr, acc[0][nt], 0,0,0);
            acc[1][nt] = __builtin_amdgcn_mfma_f32_16x16x32_bf16(a1, bfr, acc[1][nt], 0,0,0);
        }
    }
    #pragma unroll
    for (int ms = 0; ms < 2; ms++) {
        #pragma unroll
        for (int nt = 0; nt < 16; nt++) {
            int g = nt*16 + col;
            int b = b0 + wv*32 + ms*16 + q*4;
            bf16x4 o;
            o[0]=f2bf(acc[ms][nt][0]); o[1]=f2bf(acc[ms][nt][1]);
            o[2]=f2bf(acc[ms][nt][2]); o[3]=f2bf(acc[ms][nt][3]);
            *(bf16x4*)(xp0b + ((size_t)t*NG + g)*NBATCH + b) = o;
        }
    }
}

// ---------------------------------------------------------------------------
// Kernel B: depth-4 layer pipeline, 256 blocks x 256 threads (4 waves).
// Wave w owns layers {w, w+4, ..., w+20} (+ layer 24 on wave 0), one FULL
// layer-step per wave per global step (16 batch x 256 gates, 64 MFMA,
// 16 dense gate-units/lane). Skew 1 between waves; 181 barriered steps
// (vs 337 before). Recurrence is wave-local -> no cross-wave h split.
// Weights live in VGPRs (~256 regs), reloaded during the idle tt==25 step.
// Inter-wave handoff: 4-slot rings; wave3 -> wave0 (next pass, lag 23):
// 26-slot wrap ring.
// ---------------------------------------------------------------------------
__global__ __launch_bounds__(256, 1)
void lstm_persist(const short* __restrict__ whh0b, const short* __restrict__ wihRb,
                  const short* __restrict__ whhRb, const float* __restrict__ bsum,
                  const float* __restrict__ Wlin, const float* __restrict__ blin,
                  const short* __restrict__ xp0b, float* __restrict__ out) {
    __shared__ short lds[LDS_SHORTS];      // 87.5 KB rings
    __shared__ float h24[T_SEQ*HID];       // 6.4 KB: layer-24 h of batch row b0+15
    const int tid = threadIdx.x;
    const int w = tid >> 6, lane = tid & 63, col = lane & 15, q = lane >> 4;
    const int b0 = blockIdx.x << 4;
    float* __restrict__ h_n = out + 250;
    float* __restrict__ c_n = h_n + (size_t)NLAYERS*NBATCH*HID;

    bf16x8 wih[16][2], whh[16][2];
    float bias[16];
    float c16[16];
    bf16x4 xpn[16];

    // ---- preload pass-0 weights (wave w -> layer w)
    if (w == 0) {
        #pragma unroll
        for (int nt = 0; nt < 16; nt++) {
            const short* wr = whh0b + (nt*16 + col)*64;
            whh[nt][0] = *(const bf16x8*)(wr + q*8);
            whh[nt][1] = *(const bf16x8*)(wr + 32 + q*8);
            bias[nt] = 0.f;
            // prefetch xp[t=0]
            xpn[nt] = *(const bf16x4*)(xp0b + (size_t)(nt*16 + col)*NBATCH + b0 + q*4);
        }
    } else {
        const short* wi = wihRb + (w-1)*16384;
        const short* wh = whhRb + (w-1)*16384;
        #pragma unroll
        for (int nt = 0; nt < 16; nt++) {
            int g = nt*16 + col;
            wih[nt][0] = *(const bf16x8*)(wi + g*64 + q*8);
            wih[nt][1] = *(const bf16x8*)(wi + g*64 + 32 + q*8);
            whh[nt][0] = *(const bf16x8*)(wh + g*64 + q*8);
            whh[nt][1] = *(const bf16x8*)(wh + g*64 + 32 + q*8);
            bias[nt] = bsum[(w-1)*NG + g];
        }
    }
    #pragma unroll
    for (int i = 0; i < 16; i++) c16[i] = 0.f;

    int pass = 0, tt = -w;
    #pragma unroll 1
    for (int s = 0; s < 181; s++) {
        const int l = 4*pass + w;
        if (tt >= 0 && tt < 25 && l <= (w == 0 ? 24 : 23)) {
            const int t = tt;
            f32x4 acc[16];
            if (l == 0) {
                // input projection precomputed (xp0b, bias included)
                #pragma unroll
                for (int nt = 0; nt < 16; nt++) {
                    f32x4 p;
                    p[0]=bf2f(xpn[nt][0]); p[1]=bf2f(xpn[nt][1]);
                    p[2]=bf2f(xpn[nt][2]); p[3]=bf2f(xpn[nt][3]);
                    acc[nt] = p;
                }
                if (t < 24) {
                    #pragma unroll
                    for (int nt = 0; nt < 16; nt++)
                        xpn[nt] = *(const bf16x4*)(xp0b +
                            ((size_t)(t+1)*NG + nt*16 + col)*NBATCH + b0 + q*4);
                }
            } else {
                #pragma unroll
                for (int nt = 0; nt < 16; nt++)
                    acc[nt] = (f32x4){bias[nt],bias[nt],bias[nt],bias[nt]};
                // input h from producer ring: wave0 <- wrap[t], wave w <- ring[w-1][t&3]
                const int inb = (w == 0 ? WRAP_OFF + t*SLOT
                                        : (w-1)*RING_STRIDE + (t&3)*SLOT) + col*72;
                bf16x8 a0 = *(const bf16x8*)&lds[inb + q*8];
                bf16x8 a1 = *(const bf16x8*)&lds[inb + 32 + q*8];
                #pragma unroll
                for (int nt = 0; nt < 16; nt++) {
                    acc[nt] = __builtin_amdgcn_mfma_f32_16x16x32_bf16(a0, wih[nt][0], acc[nt], 0,0,0);
                    acc[nt] = __builtin_amdgcn_mfma_f32_16x16x32_bf16(a1, wih[nt][1], acc[nt], 0,0,0);
                }
            }
            if (t > 0) {
                // recurrent h: own ring slot t-1 (wave-local)
                const int rb = (w == 3 ? WRAP_OFF + (t-1)*SLOT
                                       : w*RING_STRIDE + ((t-1)&3)*SLOT) + col*72;
                bf16x8 h0 = *(const bf16x8*)&lds[rb + q*8];
                bf16x8 h1 = *(const bf16x8*)&lds[rb + 32 + q*8];
                #pragma unroll
                for (int nt = 0; nt < 16; nt++) {
                    acc[nt] = __builtin_amdgcn_mfma_f32_16x16x32_bf16(h0, whh[nt][0], acc[nt], 0,0,0);
                    acc[nt] = __builtin_amdgcn_mfma_f32_16x16x32_bf16(h1, whh[nt][1], acc[nt], 0,0,0);
                }
            }
            const int ob = (w == 3 ? WRAP_OFF + t*SLOT : w*RING_STRIDE + (t&3)*SLOT);
            // gate math: tiles are [i: 0-3][f: 4-7][g: 8-11][o: 12-15]; h = hg*16+col
            #pragma unroll
            for (int hg = 0; hg < 4; hg++) {
                #pragma unroll
                for (int rr = 0; rr < 4; rr++) {
                    float iv = acc[hg][rr],    fv = acc[4+hg][rr];
                    float gv = acc[8+hg][rr],  ov = acc[12+hg][rr];
                    float gc = fminf(fmaxf(gv, -30.f), 30.f);
                    float ei = __builtin_amdgcn_exp2f(-LOG2E * iv);
                    float eg = __builtin_amdgcn_exp2f((2.f*LOG2E) * gc);
                    float ef = __builtin_amdgcn_exp2f(-LOG2E * fv);
                    float it = (eg - 1.f) *
                        __builtin_amdgcn_rcpf((1.f + ei) * (1.f + eg));
                    float cn = __builtin_amdgcn_rcpf(1.f + ef) * c16[hg*4+rr] + it;
                    c16[hg*4+rr] = cn;
                    float cc = fminf(fmaxf(cn, -30.f), 30.f);
                    float eo = __builtin_amdgcn_exp2f(-LOG2E * ov);
                    float ec = __builtin_amdgcn_exp2f((2.f*LOG2E) * cc);
                    float hn = (ec - 1.f) *
                        __builtin_amdgcn_rcpf((1.f + eo) * (1.f + ec));
                    lds[ob + (q*4+rr)*72 + hg*16 + col] = f2bf(hn);
                    if (t == 24) {
                        size_t oi = ((size_t)l*NBATCH + b0 + q*4 + rr)*HID + hg*16 + col;
                        h_n[oi] = hn; c_n[oi] = cn;
                    }
                    if (l == 24 && q == 3 && rr == 3)
                        h24[t*HID + hg*16 + col] = hn;
                }
            }
        } else if (tt == 25) {
            // idle slot: reload weights for next pass
            int nl = 4*(pass+1) + w;
            if (nl <= (w == 0 ? 24 : 23)) {
                const short* wi = wihRb + (size_t)(nl-1)*16384;
                const short* wh = whhRb + (size_t)(nl-1)*16384;
                #pragma unroll
                for (int nt = 0; nt < 16; nt++) {
                    int g = nt*16 + col;
                    wih[nt][0] = *(const bf16x8*)(wi + g*64 + q*8);
                    wih[nt][1] = *(const bf16x8*)(wi + g*64 + 32 + q*8);
                    whh[nt][0] = *(const bf16x8*)(wh + g*64 + q*8);
                    whh[nt][1] = *(const bf16x8*)(wh + g*64 + 32 + q*8);
                    bias[nt] = bsum[(size_t)(nl-1)*NG + g];
                }
            }
            #pragma unroll
            for (int i = 0; i < 16; i++) c16[i] = 0.f;
        }
        __syncthreads();
        tt++;
        if (tt == 26) { tt = 0; pass++; }
    }

    // lstm_out = hs[:, batch 4095, :] @ Wlin^T + blin (block 255, f32 h24)
    if (blockIdx.x == 255 && tid < T_SEQ*NOUT) {
        int ti = tid / NOUT, o = tid - ti*NOUT;
        float sacc = blin[o];
        #pragma unroll
        for (int k = 0; k < HID; k++)
            sacc += h24[ti*HID + k] * Wlin[o*HID + k];
        out[tid] = sacc;
    }
}

extern "C" void kernel_launch(void* const* d_in, const int* in_sizes, int n_in,
                              void* d_out, int out_size, void* d_ws, size_t ws_size,
                              hipStream_t stream) {
    const float* x    = (const float*)d_in[0];
    const float* Wih0 = (const float*)d_in[1];
    const float* Whh0 = (const float*)d_in[2];
    const float* bih0 = (const float*)d_in[3];
    const float* bhh0 = (const float*)d_in[4];
    const float* WihR = (const float*)d_in[5];
    const float* WhhR = (const float*)d_in[6];
    const float* bihR = (const float*)d_in[7];
    const float* bhhR = (const float*)d_in[8];
    const float* Wlin = (const float*)d_in[9];
    const float* blin = (const float*)d_in[10];
    float* out = (float*)d_out;

    short* xp0b  = (short*)d_ws;            // 25*256*4096 = 26,214,400 shorts (52.4 MB)
    short* wbf2  = xp0b  + 26214400;        // 256*512 fragment-ordered
    short* whh0b = wbf2  + 131072;          // 256*64
    short* wihRb = whh0b + 16384;           // 24*256*64
    short* whhRb = wihRb + 393216;          // 24*256*64
    float* bsum  = (float*)(whhRb + 393216);// 24*256 f32

    prep<<<dim3(3672), dim3(256), 0, stream>>>(Wih0, Whh0, WihR, WhhR, bihR, bhhR,
                                               wbf2, whh0b, wihRb, whhRb, bsum);
    xp0_gemm<<<dim3(800), dim3(256), 0, stream>>>(x, wbf2, bih0, bhh0, xp0b);
    lstm_persist<<<dim3(NBATCH/16), dim3(256), 0, stream>>>(
        whh0b, wihRb, whhRb, bsum, Wlin, blin, xp0b, out);
}

// Round 2
// 889.233 us; speedup vs baseline: 1.7315x; 1.7315x over previous
//
#include <hip/hip_runtime.h>

#define T_SEQ 25
#define NBATCH 4096
#define D_IN 500
#define HID 64
#define NG 256
#define NLAYERS 25
#define NOUT 10

typedef __attribute__((ext_vector_type(8))) short bf16x8;
typedef __attribute__((ext_vector_type(4))) short bf16x4;
typedef __attribute__((ext_vector_type(4))) float f32x4;

#define LOG2E 1.4426950408889634f

// LDS geometry: slot = 16 batch rows x 72 shorts (64 h + 8 pad)
#define SLOT 1152
#define RSTRIDE (5*SLOT)                 // 5-slot small rings (4 is a race at layer wrap)
#define WRAP_OFF (3*RSTRIDE)             // 17280: wrap ring g3->g0, 25 slots by t
#define LDS_SHORTS (WRAP_OFF + 25*SLOT)  // 46080 shorts = 92.2 KB

__device__ __forceinline__ short f2bf(float f) {
    union { float f; unsigned u; } v; v.f = f;
    unsigned u = v.u + 0x7FFFu + ((v.u >> 16) & 1u);   // RNE
    return (short)(u >> 16);
}
__device__ __forceinline__ float bf2f(short s) {
    union { unsigned u; float f; } v;
    v.u = ((unsigned)(unsigned short)s) << 16;
    return v.f;
}
__device__ __forceinline__ bf16x8 cvt8(f32x4 a, f32x4 b) {
    bf16x8 r;
    r[0]=f2bf(a[0]); r[1]=f2bf(a[1]); r[2]=f2bf(a[2]); r[3]=f2bf(a[3]);
    r[4]=f2bf(b[0]); r[5]=f2bf(b[1]); r[6]=f2bf(b[2]); r[7]=f2bf(b[3]);
    return r;
}

// ---------------------------------------------------------------------------
// prep: weights -> bf16 images (unchanged).
// ---------------------------------------------------------------------------
__global__ __launch_bounds__(256)
void prep(const float* __restrict__ Wih0, const float* __restrict__ Whh0,
          const float* __restrict__ WihR, const float* __restrict__ WhhR,
          const float* __restrict__ bihR, const float* __restrict__ bhhR,
          short* __restrict__ wbf2, short* __restrict__ whh0b,
          short* __restrict__ wihRb, short* __restrict__ whhRb,
          float* __restrict__ bsum) {
    int idx = blockIdx.x * 256 + threadIdx.x;
    if (idx < 131072) {
        int j = idx & 7, lane = (idx >> 3) & 63, nt = (idx >> 9) & 15, kc = idx >> 13;
        int n = nt*16 + (lane & 15);
        int k = kc*32 + (lane >> 4)*8 + j;
        wbf2[idx] = (k < D_IN) ? f2bf(Wih0[n * D_IN + k]) : (short)0;
    } else if (idx < 147456) {
        int j = idx - 131072; whh0b[j] = f2bf(Whh0[j]);
    } else if (idx < 540672) {
        int j = idx - 147456; wihRb[j] = f2bf(WihR[j]);
    } else if (idx < 933888) {
        int j = idx - 540672; whhRb[j] = f2bf(WhhR[j]);
    } else if (idx < 940032) {
        int j = idx - 933888; bsum[j] = bihR[j] + bhhR[j];
    }
}

// ---------------------------------------------------------------------------
// Kernel A: xp0[t][g][b] (bf16) = x·W_ih0^T + bih0 + bhh0 (unchanged).
// ---------------------------------------------------------------------------
__global__ __launch_bounds__(256, 1)
void xp0_gemm(const float* __restrict__ x, const short* __restrict__ wbf2,
              const float* __restrict__ bih0, const float* __restrict__ bhh0,
              short* __restrict__ xp0b) {
    const int tid = threadIdx.x;
    const int wv = tid >> 6, lane = tid & 63, col = lane & 15, q = lane >> 4;
    const int t  = blockIdx.x >> 5;           // 32 M-tiles per t
    const int b0 = (blockIdx.x & 31) << 7;    // 128-row b tile

    f32x4 acc[2][16];
    #pragma unroll
    for (int nt = 0; nt < 16; nt++) {
        int g = nt*16 + col;
        float bv = bih0[g] + bhh0[g];
        acc[0][nt] = (f32x4){bv,bv,bv,bv};
        acc[1][nt] = acc[0][nt];
    }
    const float* xrow0 = x + ((size_t)t*NBATCH + b0 + wv*32 + col)*D_IN;
    const float* xrow1 = xrow0 + 16*(size_t)D_IN;

    #pragma unroll 3
    for (int kc = 0; kc < 15; kc++) {
        const int ko = kc*32 + q*8;
        const f32x4* p0 = (const f32x4*)(xrow0 + ko);
        const f32x4* p1 = (const f32x4*)(xrow1 + ko);
        bf16x8 a0 = cvt8(p0[0], p0[1]);
        bf16x8 a1 = cvt8(p1[0], p1[1]);
        #pragma unroll
        for (int nt = 0; nt < 16; nt++) {
            bf16x8 bfr = *(const bf16x8*)(wbf2 + ((size_t)(kc*16+nt)*64 + lane)*8);
            acc[0][nt] = __builtin_amdgcn_mfma_f32_16x16x32_bf16(a0, bfr, acc[0][nt], 0,0,0);
            acc[1][nt] = __builtin_amdgcn_mfma_f32_16x16x32_bf16(a1, bfr, acc[1][nt], 0,0,0);
        }
    }
    {   // K tail kc=15: k=480..511, valid < 500
        f32x4 z = (f32x4){0.f,0.f,0.f,0.f};
        f32x4 lo0=z, hi0=z, lo1=z, hi1=z;
        const int ko = 480 + q*8;
        if (q < 2) {
            lo0 = *(const f32x4*)(xrow0 + ko); hi0 = *(const f32x4*)(xrow0 + ko + 4);
            lo1 = *(const f32x4*)(xrow1 + ko); hi1 = *(const f32x4*)(xrow1 + ko + 4);
        } else if (q == 2) {
            lo0 = *(const f32x4*)(xrow0 + 496);
            lo1 = *(const f32x4*)(xrow1 + 496);
        }
        bf16x8 a0 = cvt8(lo0, hi0);
        bf16x8 a1 = cvt8(lo1, hi1);
        #pragma unroll
        for (int nt = 0; nt < 16; nt++) {
            bf16x8 bfr = *(const bf16x8*)(wbf2 + ((size_t)(15*16+nt)*64 + lane)*8);
            acc[0][nt] = __builtin_amdgcn_mfma_f32_16x16x32_bf16(a0, bfr, acc[0][nt], 0,0,0);
            acc[1][nt] = __builtin_amdgcn_mfma_f32_16x16x32_bf16(a1, bfr, acc[1][nt], 0,0,0);
        }
    }
    #pragma unroll
    for (int ms = 0; ms < 2; ms++) {
        #pragma unroll
        for (int nt = 0; nt < 16; nt++) {
            int g = nt*16 + col;
            int b = b0 + wv*32 + ms*16 + q*4;
            bf16x4 o;
            o[0]=f2bf(acc[ms][nt][0]); o[1]=f2bf(acc[ms][nt][1]);
            o[2]=f2bf(acc[ms][nt][2]); o[3]=f2bf(acc[ms][nt][3]);
            *(bf16x4*)(xp0b + ((size_t)t*NG + g)*NBATCH + b) = o;
        }
    }
}

// ---------------------------------------------------------------------------
// Kernel B: 4-group wrapping layer pipeline. 256 blocks x 1024 thr (16 waves).
// Group g = waves 4g..4g+3 owns layers {g, g+4, ...} (group 0 also layer 24).
// Per-wave footprint identical to the proven 88-VGPR kernel: 4 gate-tiles,
// wih[4][2]+whh[4][2] weights in regs, reloaded in-place at t==24.
// Skew 1 step between groups; 175 barriered steps total (vs 337).
// Handoff g->g+1: 5-slot LDS ring (slot = t%5). Wrap g3->g0 (lag 22):
// 25-slot ring indexed by t. wave w -> SIMD w&3 puts one wave of each group
// on every SIMD -> 4 waves/SIMD with uncorrelated phases hide stalls.
// ---------------------------------------------------------------------------
__global__ __launch_bounds__(1024, 4)
void lstm_persist(const short* __restrict__ whh0b, const short* __restrict__ wihRb,
                  const short* __restrict__ whhRb, const float* __restrict__ bsum,
                  const float* __restrict__ Wlin, const float* __restrict__ blin,
                  const short* __restrict__ xp0b, float* __restrict__ out) {
    __shared__ short lds[LDS_SHORTS];      // 92.2 KB rings
    __shared__ float h24[T_SEQ*HID];       // 6.4 KB: layer-24 h of batch row b0+15
    const int tid = threadIdx.x;
    const int w = tid >> 6, lane = tid & 63, col = lane & 15, q = lane >> 4;
    const int g = w >> 2;                  // layer-pipeline group 0..3
    const int hh = (w & 3)*16 + col;       // h column owned by this wave
    const int b0 = blockIdx.x << 4;
    float* __restrict__ h_n = out + 250;
    float* __restrict__ c_n = h_n + (size_t)NLAYERS*NBATCH*HID;

    bf16x8 wih[4][2], whh[4][2];
    float bias[4];
    float c4[4] = {0.f,0.f,0.f,0.f};
    bf16x4 xpn[4];

    // ---- initial weights: group g -> layer g
    if (g == 0) {
        #pragma unroll
        for (int gt = 0; gt < 4; gt++) {
            const short* wr = whh0b + (size_t)(gt*64 + hh)*64;
            whh[gt][0] = *(const bf16x8*)(wr + q*8);
            whh[gt][1] = *(const bf16x8*)(wr + 32 + q*8);
            wih[gt][0] = whh[gt][0]; wih[gt][1] = whh[gt][1];   // unused for l=0
            bias[gt] = 0.f;
            xpn[gt] = *(const bf16x4*)(xp0b + (size_t)(gt*64 + hh)*NBATCH + b0 + q*4);
        }
    } else {
        const short* wi = wihRb + (size_t)(g-1)*16384;
        const short* wh = whhRb + (size_t)(g-1)*16384;
        #pragma unroll
        for (int gt = 0; gt < 4; gt++) {
            int gg = gt*64 + hh;
            wih[gt][0] = *(const bf16x8*)(wi + (size_t)gg*64 + q*8);
            wih[gt][1] = *(const bf16x8*)(wi + (size_t)gg*64 + 32 + q*8);
            whh[gt][0] = *(const bf16x8*)(wh + (size_t)gg*64 + q*8);
            whh[gt][1] = *(const bf16x8*)(wh + (size_t)gg*64 + 32 + q*8);
            bias[gt] = bsum[(size_t)(g-1)*NG + gg];
        }
    }

    int pass = 0, tt = -g, s5 = 0;         // s5 == tt % 5 while tt >= 0
    #pragma unroll 1
    for (int s = 0; s < 175; s++) {
        const int l = 4*pass + g;
        if (tt >= 0 && l <= 24) {
            const int t = tt;
            f32x4 acc[4];
            if (l == 0) {
                // input projection precomputed (bias folded into xp0b)
                #pragma unroll
                for (int gt = 0; gt < 4; gt++) {
                    f32x4 p;
                    p[0]=bf2f(xpn[gt][0]); p[1]=bf2f(xpn[gt][1]);
                    p[2]=bf2f(xpn[gt][2]); p[3]=bf2f(xpn[gt][3]);
                    acc[gt] = p;
                }
                if (t < 24) {
                    #pragma unroll
                    for (int gt = 0; gt < 4; gt++)
                        xpn[gt] = *(const bf16x4*)(xp0b +
                            ((size_t)(t+1)*NG + gt*64 + hh)*NBATCH + b0 + q*4);
                }
            } else {
                #pragma unroll
                for (int gt = 0; gt < 4; gt++)
                    acc[gt] = (f32x4){bias[gt],bias[gt],bias[gt],bias[gt]};
                // input = previous layer's h: group 0 from wrap ring, else ring g-1
                const int inb = (g == 0 ? WRAP_OFF + t*SLOT
                                        : (g-1)*RSTRIDE + s5*SLOT) + col*72;
                bf16x8 a0 = *(const bf16x8*)&lds[inb + q*8];
                bf16x8 a1 = *(const bf16x8*)&lds[inb + 32 + q*8];
                #pragma unroll
                for (int gt = 0; gt < 4; gt++) {
                    acc[gt] = __builtin_amdgcn_mfma_f32_16x16x32_bf16(a0, wih[gt][0], acc[gt], 0,0,0);
                    acc[gt] = __builtin_amdgcn_mfma_f32_16x16x32_bf16(a1, wih[gt][1], acc[gt], 0,0,0);
                }
            }
            if (t > 0) {
                // recurrent h: own output slot t-1 (barrier-separated)
                const int p5 = (s5 == 0) ? 4 : s5 - 1;
                const int rb = (g == 3 ? WRAP_OFF + (t-1)*SLOT
                                       : g*RSTRIDE + p5*SLOT) + col*72;
                bf16x8 h0 = *(const bf16x8*)&lds[rb + q*8];
                bf16x8 h1 = *(const bf16x8*)&lds[rb + 32 + q*8];
                #pragma unroll
                for (int gt = 0; gt < 4; gt++) {
                    acc[gt] = __builtin_amdgcn_mfma_f32_16x16x32_bf16(h0, whh[gt][0], acc[gt], 0,0,0);
                    acc[gt] = __builtin_amdgcn_mfma_f32_16x16x32_bf16(h1, whh[gt][1], acc[gt], 0,0,0);
                }
            }
            const int ob = (g == 3 ? WRAP_OFF + t*SLOT : g*RSTRIDE + s5*SLOT);
            // gates: acc[0..3] = i,f,g,o tiles; batch row q*4+rr, h col hh
            #pragma unroll
            for (int rr = 0; rr < 4; rr++) {
                float iv = acc[0][rr], fv = acc[1][rr];
                float gv = acc[2][rr], ov = acc[3][rr];
                float gc = fminf(fmaxf(gv, -30.f), 30.f);
                float ei = __builtin_amdgcn_exp2f(-LOG2E * iv);
                float eg = __builtin_amdgcn_exp2f((2.f*LOG2E) * gc);
                float ef = __builtin_amdgcn_exp2f(-LOG2E * fv);
                float it = (eg - 1.f) *
                    __builtin_amdgcn_rcpf((1.f + ei) * (1.f + eg));
                float cn = __builtin_amdgcn_rcpf(1.f + ef) * c4[rr] + it;
                c4[rr] = cn;
                float cc = fminf(fmaxf(cn, -30.f), 30.f);
                float eo = __builtin_amdgcn_exp2f(-LOG2E * ov);
                float ec = __builtin_amdgcn_exp2f((2.f*LOG2E) * cc);
                float hn = (ec - 1.f) *
                    __builtin_amdgcn_rcpf((1.f + eo) * (1.f + ec));
                lds[ob + (q*4+rr)*72 + hh] = f2bf(hn);
                if (t == 24) {
                    size_t oi = ((size_t)l*NBATCH + b0 + q*4 + rr)*HID + hh;
                    h_n[oi] = hn; c_n[oi] = cn;
                }
                if (l == 24 && q == 3 && rr == 3)
                    h24[t*HID + hh] = hn;
            }
            if (t == 24) {
                // in-place weight reload for next layer (after last use)
                const int nl = l + 4;
                if (nl <= 24) {
                    const short* wi = wihRb + (size_t)(nl-1)*16384;
                    const short* wh = whhRb + (size_t)(nl-1)*16384;
                    #pragma unroll
                    for (int gt = 0; gt < 4; gt++) {
                        int gg = gt*64 + hh;
                        wih[gt][0] = *(const bf16x8*)(wi + (size_t)gg*64 + q*8);
                        wih[gt][1] = *(const bf16x8*)(wi + (size_t)gg*64 + 32 + q*8);
                        whh[gt][0] = *(const bf16x8*)(wh + (size_t)gg*64 + q*8);
                        whh[gt][1] = *(const bf16x8*)(wh + (size_t)gg*64 + 32 + q*8);
                        bias[gt] = bsum[(size_t)(nl-1)*NG + gg];
                    }
                }
                c4[0]=c4[1]=c4[2]=c4[3]=0.f;
            }
        }
        __syncthreads();
        tt++;
        if (tt == 25) { tt = 0; pass++; s5 = 0; }
        else if (tt > 0) { s5++; if (s5 == 5) s5 = 0; }
    }

    // lstm_out = hs[:, batch 4095, :] @ Wlin^T + blin (block 255, f32 h24)
    if (blockIdx.x == 255 && tid < T_SEQ*NOUT) {
        int ti = tid / NOUT, o = tid - ti*NOUT;
        float sacc = blin[o];
        #pragma unroll
        for (int k = 0; k < HID; k++)
            sacc += h24[ti*HID + k] * Wlin[o*HID + k];
        out[tid] = sacc;
    }
}

extern "C" void kernel_launch(void* const* d_in, const int* in_sizes, int n_in,
                              void* d_out, int out_size, void* d_ws, size_t ws_size,
                              hipStream_t stream) {
    const float* x    = (const float*)d_in[0];
    const float* Wih0 = (const float*)d_in[1];
    const float* Whh0 = (const float*)d_in[2];
    const float* bih0 = (const float*)d_in[3];
    const float* bhh0 = (const float*)d_in[4];
    const float* WihR = (const float*)d_in[5];
    const float* WhhR = (const float*)d_in[6];
    const float* bihR = (const float*)d_in[7];
    const float* bhhR = (const float*)d_in[8];
    const float* Wlin = (const float*)d_in[9];
    const float* blin = (const float*)d_in[10];
    float* out = (float*)d_out;

    short* xp0b  = (short*)d_ws;            // 25*256*4096 = 26,214,400 shorts (52.4 MB)
    short* wbf2  = xp0b  + 26214400;        // 256*512 fragment-ordered
    short* whh0b = wbf2  + 131072;          // 256*64
    short* wihRb = whh0b + 16384;           // 24*256*64
    short* whhRb = wihRb + 393216;          // 24*256*64
    float* bsum  = (float*)(whhRb + 393216);// 24*256 f32

    prep<<<dim3(3672), dim3(256), 0, stream>>>(Wih0, Whh0, WihR, WhhR, bihR, bhhR,
                                               wbf2, whh0b, wihRb, whhRb, bsum);
    xp0_gemm<<<dim3(800), dim3(256), 0, stream>>>(x, wbf2, bih0, bhh0, xp0b);
    lstm_persist<<<dim3(NBATCH/16), dim3(1024), 0, stream>>>(
        whh0b, wihRb, whhRb, bsum, Wlin, blin, xp0b, out);
}